// Round 9
// baseline (91.926 us; speedup 1.0000x reference)
//
#include <hip/hip_runtime.h>
#include <hip/hip_bf16.h>

// Y[b,o,hw] = mean_i(W[i,o,:]) . x[b,:,hw] + mean_i(B[i,o])
// B=16, Cin=Cout=64, HW=65536, fp32 in/out.
// R9 = R8 minus the block barrier: WAVE-PRIVATE LDS staging.
// Each wave stages its own 8KB [64c][32p] quarter via global_load_lds and
// waits only its own vmcnt(0). No __syncthreads anywhere -> no convoy;
// 20 independent waves/CU hide DMA latency. Compute/store = R7/R8-verified.

#define HW 65536
#define CIN 64
#define COUT 64
#define NB 16
#define NCONV 9
#define TP 128   // positions per block (32 per wave)

typedef short s16x8 __attribute__((ext_vector_type(8)));
typedef float f32x16 __attribute__((ext_vector_type(16)));

// float -> bf16 (RNE) raw bits
static __device__ __forceinline__ unsigned short f2bf(float f) {
    unsigned u = __builtin_bit_cast(unsigned, f);
    u = (u + 0x7FFFu + ((u >> 16) & 1u)) >> 16;
    return (unsigned short)u;
}

// ---- pre-kernel: ws[0..8191]B = Wm[o][c] bf16; ws+8192: Bm[64] fp32 ----
__global__ void reduce_wb_kernel(const float* __restrict__ w,
                                 const float* __restrict__ b,
                                 void* __restrict__ wsv) {
    unsigned short* wm = (unsigned short*)wsv;
    float* bm = (float*)((char*)wsv + 8192);
    int tid = blockIdx.x * blockDim.x + threadIdx.x;
    const float inv9 = 1.0f / 9.0f;
    if (tid < COUT * CIN) {
        float s = 0.f;
        #pragma unroll
        for (int i = 0; i < NCONV; ++i) s += w[i * (COUT * CIN) + tid];
        wm[tid] = f2bf(s * inv9);
    } else if (tid < COUT * CIN + COUT) {
        int o = tid - COUT * CIN;
        float s = 0.f;
        #pragma unroll
        for (int i = 0; i < NCONV; ++i) s += b[i * COUT + o];
        bm[o] = s * inv9;
    }
}

// ---- main kernel ----
__global__ __launch_bounds__(256, 5) void conv1x1_wavepriv_kernel(
        const float* __restrict__ x,
        const void* __restrict__ wsv,
        float* __restrict__ out) {
    // 4 wave-private quarters: [wave][64 c][32 p] floats = 4 x 8KB = 32KB
    __shared__ float lds[4 * CIN * 32];

    const unsigned short* wm = (const unsigned short*)wsv;     // bf16 [64][64]
    const float* bm = (const float*)((const char*)wsv + 8192); // fp32 [64]

    const int tid  = threadIdx.x;
    const int lane = tid & 63;
    const int wave = tid >> 6;    // 0..3
    const int l31  = lane & 31;
    const int lh   = lane >> 5;   // 0/1

    unsigned pbase = blockIdx.x * (unsigned)TP;
    unsigned img   = pbase >> 16;                 // HW = 2^16, TP | HW
    unsigned p0    = pbase & 65535u;
    // this wave's 32 positions start here:
    unsigned pw    = p0 + (unsigned)(wave * 32);
    const float* __restrict__ xw = x   + (size_t)img * CIN  * HW + pw;
    float* __restrict__       ow = out + (size_t)img * COUT * HW + pw;

    float* __restrict__ lq = &lds[wave * (CIN * 32)];   // this wave's quarter

    // ---- A fragments + bias (latency overlaps DMA issue below) ----
    // afrag[m][kk][j] = W[o = m*32 + l31][c = kk*16 + lh*8 + j]  (verified)
    s16x8 afrag[2][4];
    #pragma unroll
    for (int m = 0; m < 2; ++m) {
        #pragma unroll
        for (int kk = 0; kk < 4; ++kk) {
            afrag[m][kk] = *reinterpret_cast<const s16x8*>(
                wm + (m * 32 + l31) * CIN + kk * 16 + lh * 8);
        }
    }
    f32x16 acc[2];
    #pragma unroll
    for (int m = 0; m < 2; ++m) {
        #pragma unroll
        for (int r = 0; r < 16; ++r) {
            acc[m][r] = bm[m * 32 + (r & 3) + 8 * (r >> 2) + 4 * lh];
        }
    }

    // ---- wave-private async stage: 8 instrs, 1KB each = 8 channels x 32 pos
    // instr i: lane l -> channel c = i*8 + (l>>3), pos off = (l&7)*4.
    // LDS dst is lane-linear (base + l*16B) == [c][32p] layout exactly:
    // float off = i*256 + l*4 = c*32 + p.
    {
        #pragma unroll
        for (int i = 0; i < 8; ++i) {
            const float* src = xw + (size_t)(i * 8 + (lane >> 3)) * HW
                                  + (unsigned)((lane & 7) * 4);
            __builtin_amdgcn_global_load_lds(
                (const __attribute__((address_space(1))) unsigned int*)src,
                (__attribute__((address_space(3))) unsigned int*)&lq[i * 256],
                16, 0, 0);
        }
    }

    // wait for THIS WAVE's DMA only -- no barrier, no cross-wave coupling
    asm volatile("s_waitcnt vmcnt(0)" ::: "memory");

    // ---- B fragments: bfrag[kk][j] = X[c = kk*16 + lh*8 + j][p = l31]
    // addr = c*32 + l31: lanes 0-31 distinct banks; 32-63 2-way alias (free).
    s16x8 bfrag[4];
    #pragma unroll
    for (int kk = 0; kk < 4; ++kk) {
        float xf[8];
        #pragma unroll
        for (int j = 0; j < 8; ++j)
            xf[j] = lq[(kk * 16 + lh * 8 + j) * 32 + l31];
        #pragma unroll
        for (int j = 0; j < 8; ++j)
            bfrag[kk][j] = (short)f2bf(xf[j]);
    }

    #pragma unroll
    for (int kk = 0; kk < 4; ++kk) {
        acc[0] = __builtin_amdgcn_mfma_f32_32x32x16_bf16(
            afrag[0][kk], bfrag[kk], acc[0], 0, 0, 0);
        acc[1] = __builtin_amdgcn_mfma_f32_32x32x16_bf16(
            afrag[1][kk], bfrag[kk], acc[1], 0, 0, 0);
    }

    // ---- direct nt-stores: each (m,r) instr = 128B full line per half-wave
    float* op = ow + (unsigned)l31;
    #pragma unroll
    for (int m = 0; m < 2; ++m) {
        #pragma unroll
        for (int r = 0; r < 16; ++r) {
            int o = m * 32 + (r & 3) + 8 * (r >> 2) + 4 * lh;
            __builtin_nontemporal_store(acc[m][r], op + (size_t)o * HW);
        }
    }
}

extern "C" void kernel_launch(void* const* d_in, const int* in_sizes, int n_in,
                              void* d_out, int out_size, void* d_ws, size_t ws_size,
                              hipStream_t stream) {
    const float* x = (const float*)d_in[0];   // [16][64][256][256]
    const float* w = (const float*)d_in[1];   // [9][64][64][1][1]
    const float* b = (const float*)d_in[2];   // [9][64]
    float* out = (float*)d_out;

    int red_items  = COUT * CIN + COUT;        // 4160
    int red_blocks = (red_items + 255) / 256;  // 17
    reduce_wb_kernel<<<red_blocks, 256, 0, stream>>>(w, b, d_ws);

    unsigned total_blocks = (NB * HW) / TP;    // 8192
    conv1x1_wavepriv_kernel<<<total_blocks, 256, 0, stream>>>(x, d_ws, out);
}